// Round 2
// baseline (569.258 us; speedup 1.0000x reference)
//
#include <hip/hip_runtime.h>
#include <hip/hip_bf16.h>
#include <stdint.h>

typedef __bf16 bf16;
typedef __bf16 bf16x4 __attribute__((ext_vector_type(4)));
typedef __bf16 bf16x8 __attribute__((ext_vector_type(8)));
typedef float  f32x4  __attribute__((ext_vector_type(4)));
typedef float  f32x2  __attribute__((ext_vector_type(2)));

#define NROWS 262144
#define GSEG  65536
#define DIN   512
#define DMID  256
#define DGAT  128
#define DOUT  256

// ---- workspace layout (bytes) ----
#define OFF_W2T   0u           // [256][512] bf16
#define OFF_W3T   262144u      // [128][256] bf16
#define OFF_GWT   327680u      // [128][128] bf16
#define OFF_BNS   360448u      // [256] f32
#define OFF_BNB   361472u      // [256] f32
#define OFF_RS    362496u      // [65537] int
#define OFF_H1    1048576u     // [NROWS][256] bf16
#define OFF_H2    135266304u   // [NROWS][128] f32
#define OFF_G     269484032u   // [NROWS][128] f32
#define OFF_E     403701760u   // [NROWS] f32
#define OFF_OBJ   404750336u   // [GSEG][128] f32

// XOR-swizzle element index within a row: flip bits 3..5 by row&7.
__device__ __forceinline__ int swz(int r, int k) { return k ^ ((r & 7) << 3); }

#define GLOAD16(gptr, lptr) __builtin_amdgcn_global_load_lds( \
    (const __attribute__((address_space(1))) void*)(gptr),    \
    (__attribute__((address_space(3))) void*)(lptr), 16, 0, 0)

// ---------------- prep ----------------
__global__ __launch_bounds__(256) void k_prep(
    const float* __restrict__ w2, const float* __restrict__ w3, const float* __restrict__ gw,
    const float* __restrict__ b2, const float* __restrict__ bn_g, const float* __restrict__ bn_b,
    const float* __restrict__ bn_m, const float* __restrict__ bn_v,
    bf16* __restrict__ w2t, bf16* __restrict__ w3t, bf16* __restrict__ gwt,
    float* __restrict__ bnS, float* __restrict__ bnB) {
  int idx = blockIdx.x * 256 + threadIdx.x;
  if (idx < DIN * DMID) { int k = idx / DMID, n = idx % DMID; w2t[n * DIN + k] = (bf16)w2[idx]; }
  if (idx < DMID * DGAT) { int k = idx / DGAT, n = idx % DGAT; w3t[n * DMID + k] = (bf16)w3[idx]; }
  if (idx < DGAT * DGAT) { int k = idx / DGAT, n = idx % DGAT; gwt[n * DGAT + k] = (bf16)gw[idx]; }
  if (idx < DMID) {
    float s = bn_g[idx] * rsqrtf(bn_v[idx] + 1e-5f);
    bnS[idx] = s;
    bnB[idx] = s * (b2[idx] - bn_m[idx]) + bn_b[idx];
  }
}

// ---------------- segment boundaries ----------------
__global__ __launch_bounds__(256) void k_rowstart(const int* __restrict__ seg, int* __restrict__ rs) {
  int i = blockIdx.x * 256 + threadIdx.x;
  if (i >= NROWS) return;
  int s = seg[i];
  if (i == 0) rs[s] = 0;
  else if (seg[i - 1] != s) rs[s] = i;
  if (i == NROWS - 1) rs[GSEG] = NROWS;
}

// ---------------- GEMM1: h1 = relu(bnS*(x@w2)+bnB) ----------------
// tile 64x256, 256 threads (4 waves 1x4), wave tile 64x64, BK=64, dbuf A-LDS,
// reg-prefetch x, B-frags straight from L2-resident w2t, swapped MFMA.
__global__ __launch_bounds__(256) void k_gemm1(
    const float* __restrict__ x, const bf16* __restrict__ w2t,
    const float* __restrict__ bnS, const float* __restrict__ bnB,
    bf16* __restrict__ h1) {
  __shared__ bf16 As[2][64 * 64];
  const int t = threadIdx.x;
  const int mBase = blockIdx.x * 64;
  const int w = t >> 6, l = t & 63;          // wn = w (0..3)
  const int l15 = l & 15, lh = l >> 4;

  // A staging: 4 threads per row, 16 floats each
  const int sr = t >> 2;                     // 0..63
  const int sk = (t & 3) * 16;               // 0,16,32,48
  const float* xrow = x + (size_t)(mBase + sr) * DIN + sk;
  bf16* aw0 = &As[0][sr * 64 + swz(sr, sk)];
  bf16* aw1 = &As[0][sr * 64 + swz(sr, sk + 8)];

  f32x4 acc[4][4];
  const f32x4 zero = {0.f, 0.f, 0.f, 0.f};
#pragma unroll
  for (int m = 0; m < 4; m++)
#pragma unroll
    for (int n = 0; n < 4; n++) acc[m][n] = zero;

  float4 pf0 = *(const float4*)(xrow + 0);
  float4 pf1 = *(const float4*)(xrow + 4);
  float4 pf2 = *(const float4*)(xrow + 8);
  float4 pf3 = *(const float4*)(xrow + 12);

#pragma unroll
  for (int kt = 0; kt < 8; ++kt) {
    const int c = kt & 1;
    // write staged A (tile kt) into As[c]
    bf16x8 lo, hi;
    lo[0]=(bf16)pf0.x; lo[1]=(bf16)pf0.y; lo[2]=(bf16)pf0.z; lo[3]=(bf16)pf0.w;
    lo[4]=(bf16)pf1.x; lo[5]=(bf16)pf1.y; lo[6]=(bf16)pf1.z; lo[7]=(bf16)pf1.w;
    hi[0]=(bf16)pf2.x; hi[1]=(bf16)pf2.y; hi[2]=(bf16)pf2.z; hi[3]=(bf16)pf2.w;
    hi[4]=(bf16)pf3.x; hi[5]=(bf16)pf3.y; hi[6]=(bf16)pf3.z; hi[7]=(bf16)pf3.w;
    *(bf16x8*)(aw0 + c * 4096) = lo;
    *(bf16x8*)(aw1 + c * 4096) = hi;
    __syncthreads();
    // prefetch next x tile (overlaps MFMA below, drained after MFMA)
    if (kt < 7) {
      pf0 = *(const float4*)(xrow + (kt + 1) * 64 + 0);
      pf1 = *(const float4*)(xrow + (kt + 1) * 64 + 4);
      pf2 = *(const float4*)(xrow + (kt + 1) * 64 + 8);
      pf3 = *(const float4*)(xrow + (kt + 1) * 64 + 12);
    }
#pragma unroll
    for (int ks = 0; ks < 2; ++ks) {
      const int kofs = ks * 32 + lh * 8;
      bf16x8 a[4], b[4];
#pragma unroll
      for (int n = 0; n < 4; n++) {
        int cn = w * 64 + n * 16 + l15;
        b[n] = *(const bf16x8*)(w2t + (size_t)cn * DIN + kt * 64 + kofs);
      }
#pragma unroll
      for (int m = 0; m < 4; m++) {
        int r = m * 16 + l15;
        a[m] = *(const bf16x8*)(&As[c][r * 64 + swz(r, kofs)]);
      }
#pragma unroll
      for (int m = 0; m < 4; m++)
#pragma unroll
        for (int n = 0; n < 4; n++)
          acc[m][n] = __builtin_amdgcn_mfma_f32_16x16x32_bf16(b[n], a[m], acc[m][n], 0, 0, 0);
    }
  }
  // epilogue: lane holds row r = m*16+(l&15), cols c0..c0+3 -> packed bf16x4
#pragma unroll
  for (int n = 0; n < 4; n++) {
    int c0 = w * 64 + n * 16 + lh * 4;
    f32x4 s4 = *(const f32x4*)(bnS + c0);
    f32x4 b4 = *(const f32x4*)(bnB + c0);
#pragma unroll
    for (int m = 0; m < 4; m++) {
      int r = mBase + m * 16 + l15;
      bf16x4 o;
#pragma unroll
      for (int q = 0; q < 4; q++) {
        float v = acc[m][n][q] * s4[q] + b4[q];
        o[q] = (bf16)(v > 0.f ? v : 0.f);
      }
      *(bf16x4*)(h1 + (size_t)r * DMID + c0) = o;
    }
  }
}

// ---------------- GEMM2+3 fused ----------------
// tile 128x128, 256 threads (4 waves 2x2), wave tile 64x64.
// A (h1) via global_load_lds w/ pre-swizzled source, dbuf, 1 barrier/K-step.
// w3t & gwt fragments from L2. Swapped MFMA -> packed f32x4 stores.
__global__ __launch_bounds__(256) void k_gemm23(
    const bf16* __restrict__ h1, const bf16* __restrict__ w3t, const bf16* __restrict__ gwt,
    const float* __restrict__ b3, const float* __restrict__ gb, const float* __restrict__ ga,
    float* __restrict__ h2, float* __restrict__ g, float* __restrict__ e) {
  __shared__ bf16 As[2][128 * 64];   // 32 KB; phase2 Hs aliases both buffers
  __shared__ float eP[256];
  bf16* Hs = &As[0][0];
  const int t = threadIdx.x;
  const int mBase = blockIdx.x * 128;
  const int w = t >> 6, l = t & 63;
  const int wm = w >> 1, wn = w & 1;
  const int l15 = l & 15, lh = l >> 4;
  const f32x4 zero = {0.f, 0.f, 0.f, 0.f};

  // global_load_lds staging: per wave 4 instrs, 1KB each; source pre-swizzled
  const int rr8 = l >> 3;                      // row within 8-row chunk
  const int jb = ((l & 7) ^ rr8) << 3;         // swizzled elem offset
#define GL_TILE(kt, buf)                                                        \
  {                                                                             \
    _Pragma("unroll")                                                           \
    for (int i = 0; i < 4; i++) {                                               \
      const int w4i = w * 4 + i;                                                \
      const int rr = w4i * 8 + rr8;                                             \
      GLOAD16(h1 + (size_t)(mBase + rr) * DMID + (kt) * 64 + jb,                \
              &As[buf][w4i * 512]);                                             \
    }                                                                           \
  }

  f32x4 acc[4][4];
#pragma unroll
  for (int m = 0; m < 4; m++)
#pragma unroll
    for (int n = 0; n < 4; n++) acc[m][n] = zero;

  GL_TILE(0, 0)
  // phase 1: h2 = relu(h1@w3+b3), K=256
#pragma unroll
  for (int kt = 0; kt < 4; ++kt) {
    const int c = kt & 1;
    __syncthreads();                // drains tile kt into As[c]
    if (kt < 3) GL_TILE(kt + 1, c ^ 1)
#pragma unroll
    for (int ks = 0; ks < 2; ++ks) {
      const int kofs = ks * 32 + lh * 8;
      bf16x8 a[4], b[4];
#pragma unroll
      for (int n = 0; n < 4; n++) {
        int cn = wn * 64 + n * 16 + l15;
        b[n] = *(const bf16x8*)(w3t + (size_t)cn * DMID + kt * 64 + kofs);
      }
#pragma unroll
      for (int m = 0; m < 4; m++) {
        int r = wm * 64 + m * 16 + l15;
        a[m] = *(const bf16x8*)(&As[c][r * 64 + swz(r, kofs)]);
      }
#pragma unroll
      for (int m = 0; m < 4; m++)
#pragma unroll
        for (int n = 0; n < 4; n++)
          acc[m][n] = __builtin_amdgcn_mfma_f32_16x16x32_bf16(b[n], a[m], acc[m][n], 0, 0, 0);
    }
  }
  __syncthreads();   // all MFMA reads of As done before Hs overwrite

  // epilogue 1: relu+bias; packed f32x4 to h2, bf16x4 to Hs (swizzled)
#pragma unroll
  for (int n = 0; n < 4; n++) {
    int c0 = wn * 64 + n * 16 + lh * 4;
    f32x4 b4 = *(const f32x4*)(b3 + c0);
#pragma unroll
    for (int m = 0; m < 4; m++) {
      int rl = wm * 64 + m * 16 + l15;
      f32x4 v;
      bf16x4 hb;
#pragma unroll
      for (int q = 0; q < 4; q++) {
        float vv = acc[m][n][q] + b4[q];
        vv = vv > 0.f ? vv : 0.f;
        v[q] = vv;
        hb[q] = (bf16)vv;
      }
      *(f32x4*)(h2 + (size_t)(mBase + rl) * DGAT + c0) = v;
      *(bf16x4*)(Hs + rl * 128 + swz(rl, c0)) = hb;
    }
  }
  __syncthreads();

  // phase 2: g = h2@gw+gb (K=128), B-frags from L2-resident gwt
  f32x4 gacc[4][4];
#pragma unroll
  for (int m = 0; m < 4; m++)
#pragma unroll
    for (int n = 0; n < 4; n++) gacc[m][n] = zero;
#pragma unroll
  for (int ks = 0; ks < 4; ++ks) {
    const int kofs = ks * 32 + lh * 8;
    bf16x8 a[4], b[4];
#pragma unroll
    for (int n = 0; n < 4; n++) {
      int cn = wn * 64 + n * 16 + l15;
      b[n] = *(const bf16x8*)(gwt + (size_t)cn * DGAT + kofs);
    }
#pragma unroll
    for (int m = 0; m < 4; m++) {
      int r = wm * 64 + m * 16 + l15;
      a[m] = *(const bf16x8*)(Hs + r * 128 + swz(r, kofs));
    }
#pragma unroll
    for (int m = 0; m < 4; m++)
#pragma unroll
      for (int n = 0; n < 4; n++)
        gacc[m][n] = __builtin_amdgcn_mfma_f32_16x16x32_bf16(b[n], a[m], gacc[m][n], 0, 0, 0);
  }
  // epilogue 2: packed g stores + e = g.ga
  float ep[4] = {0.f, 0.f, 0.f, 0.f};
#pragma unroll
  for (int n = 0; n < 4; n++) {
    int c0 = wn * 64 + n * 16 + lh * 4;
    f32x4 gb4 = *(const f32x4*)(gb + c0);
    f32x4 ga4 = *(const f32x4*)(ga + c0);
#pragma unroll
    for (int m = 0; m < 4; m++) {
      int rl = wm * 64 + m * 16 + l15;
      f32x4 gv;
#pragma unroll
      for (int q = 0; q < 4; q++) gv[q] = gacc[m][n][q] + gb4[q];
      *(f32x4*)(g + (size_t)(mBase + rl) * DGAT + c0) = gv;
#pragma unroll
      for (int q = 0; q < 4; q++) ep[m] += gv[q] * ga4[q];
    }
  }
#pragma unroll
  for (int m = 0; m < 4; m++) {
    float v = ep[m];
    v += __shfl_xor(v, 16, 64);
    v += __shfl_xor(v, 32, 64);
    if (l < 16) eP[(wm * 64 + m * 16 + l) * 2 + wn] = v;
  }
  __syncthreads();
  if (t < 128) e[mBase + t] = eP[t * 2] + eP[t * 2 + 1];
}

// ---------------- segment softmax-pool + residual + segment max ----------------
__global__ __launch_bounds__(256) void k_seg(
    const float* __restrict__ e, const float* __restrict__ g, const float* __restrict__ h2,
    const int* __restrict__ rs, float* __restrict__ obj) {
  const int w = threadIdx.x >> 6, l = threadIdx.x & 63;
  const int s = blockIdx.x * 4 + w;
  const int r0 = rs[s], r1 = rs[s + 1];
  float m = -3.4e38f;
  for (int r = r0; r < r1; ++r) m = fmaxf(m, e[r]);
  float den = 0.f;
  f32x2 p = {0.f, 0.f};
  for (int r = r0; r < r1; ++r) {
    float wr = __expf(e[r] - m);
    den += wr;
    f32x2 gv = *(const f32x2*)(g + (size_t)r * DGAT + l * 2);
    p[0] += wr * gv[0];
    p[1] += wr * gv[1];
  }
  float inv = 1.f / den;
  p[0] *= inv; p[1] *= inv;
  f32x2 om = {0.f, 0.f};
  for (int r = r0; r < r1; ++r) {
    f32x2 hv = *(const f32x2*)(h2 + (size_t)r * DGAT + l * 2);
    om[0] = fmaxf(om[0], fmaxf(hv[0] + p[0], 0.f));
    om[1] = fmaxf(om[1], fmaxf(hv[1] + p[1], 0.f));
  }
  *(f32x2*)(obj + (size_t)s * DGAT + l * 2) = om;
}

// ---------------- projection + L2 norm ----------------
__global__ __launch_bounds__(256) void k_proj(
    const float* __restrict__ obj, const float* __restrict__ pw, const float* __restrict__ pb,
    float* __restrict__ out) {
  __shared__ float objs[16 * 128];
  __shared__ float red[16 * 4];
  const int t = threadIdx.x;
  const int gBase = blockIdx.x * 16;
#pragma unroll
  for (int i = 0; i < 8; i++) {
    int idx = i * 256 + t;
    objs[idx] = obj[(size_t)gBase * 128 + idx];
  }
  __syncthreads();
  float acc[16];
#pragma unroll
  for (int r = 0; r < 16; r++) acc[r] = 0.f;
  for (int k4 = 0; k4 < 32; k4++) {
    float p0 = pw[(k4 * 4 + 0) * 256 + t];
    float p1 = pw[(k4 * 4 + 1) * 256 + t];
    float p2 = pw[(k4 * 4 + 2) * 256 + t];
    float p3 = pw[(k4 * 4 + 3) * 256 + t];
#pragma unroll
    for (int r = 0; r < 16; r++) {
      f32x4 o = *(const f32x4*)(objs + r * 128 + k4 * 4);
      acc[r] += o[0] * p0 + o[1] * p1 + o[2] * p2 + o[3] * p3;
    }
  }
  const float pbv = pb[t];
  const int w = t >> 6, l = t & 63;
#pragma unroll
  for (int r = 0; r < 16; r++) {
    acc[r] += pbv;
    float s2 = acc[r] * acc[r];
#pragma unroll
    for (int off = 32; off >= 1; off >>= 1) s2 += __shfl_xor(s2, off, 64);
    if (l == 0) red[r * 4 + w] = s2;
  }
  __syncthreads();
#pragma unroll
  for (int r = 0; r < 16; r++) {
    float tot = red[r * 4] + red[r * 4 + 1] + red[r * 4 + 2] + red[r * 4 + 3];
    float rinv = 1.f / (sqrtf(tot) + 1e-9f);
    out[(size_t)(gBase + r) * 256 + t] = acc[r] * rinv;
  }
}

extern "C" void kernel_launch(void* const* d_in, const int* in_sizes, int n_in,
                              void* d_out, int out_size, void* d_ws, size_t ws_size,
                              hipStream_t stream) {
  const float* x    = (const float*)d_in[0];
  const int*   seg  = (const int*)d_in[1];
  const float* w2   = (const float*)d_in[2];
  const float* b2   = (const float*)d_in[3];
  const float* bn_g = (const float*)d_in[4];
  const float* bn_b = (const float*)d_in[5];
  const float* bn_m = (const float*)d_in[6];
  const float* bn_v = (const float*)d_in[7];
  const float* w3   = (const float*)d_in[8];
  const float* b3   = (const float*)d_in[9];
  const float* gw   = (const float*)d_in[10];
  const float* gb   = (const float*)d_in[11];
  const float* ga   = (const float*)d_in[12];
  const float* pw   = (const float*)d_in[13];
  const float* pb   = (const float*)d_in[14];

  char* ws = (char*)d_ws;
  bf16*  w2t = (bf16*)(ws + OFF_W2T);
  bf16*  w3t = (bf16*)(ws + OFF_W3T);
  bf16*  gwt = (bf16*)(ws + OFF_GWT);
  float* bnS = (float*)(ws + OFF_BNS);
  float* bnB = (float*)(ws + OFF_BNB);
  int*   rs  = (int*)(ws + OFF_RS);
  bf16*  h1  = (bf16*)(ws + OFF_H1);
  float* h2  = (float*)(ws + OFF_H2);
  float* g   = (float*)(ws + OFF_G);
  float* e   = (float*)(ws + OFF_E);
  float* obj = (float*)(ws + OFF_OBJ);
  float* out = (float*)d_out;

  k_prep<<<512, 256, 0, stream>>>(w2, w3, gw, b2, bn_g, bn_b, bn_m, bn_v, w2t, w3t, gwt, bnS, bnB);
  k_rowstart<<<NROWS / 256, 256, 0, stream>>>(seg, rs);
  k_gemm1<<<NROWS / 64, 256, 0, stream>>>(x, w2t, bnS, bnB, h1);
  k_gemm23<<<NROWS / 128, 256, 0, stream>>>(h1, w3t, gwt, b3, gb, ga, h2, g, e);
  k_seg<<<GSEG / 4, 256, 0, stream>>>(e, g, h2, rs, obj);
  k_proj<<<GSEG / 16, 256, 0, stream>>>(obj, pw, pb, out);
}

// Round 3
// 459.478 us; speedup vs baseline: 1.2389x; 1.2389x over previous
//
#include <hip/hip_runtime.h>
#include <hip/hip_bf16.h>
#include <stdint.h>

typedef __bf16 bf16;
typedef __bf16 bf16x2 __attribute__((ext_vector_type(2)));
typedef __bf16 bf16x4 __attribute__((ext_vector_type(4)));
typedef __bf16 bf16x8 __attribute__((ext_vector_type(8)));
typedef float  f32x4  __attribute__((ext_vector_type(4)));
typedef float  f32x2  __attribute__((ext_vector_type(2)));

#define NROWS 262144
#define GSEG  65536
#define DIN   512
#define DMID  256
#define DGAT  128
#define DOUT  256

// ---- workspace layout (bytes) ----
#define OFF_W2T   0u           // [256][512] bf16
#define OFF_W3T   262144u      // [128][256] bf16
#define OFF_GWT   327680u      // [128][128] bf16
#define OFF_BNS   360448u      // [256] f32
#define OFF_BNB   361472u      // [256] f32
#define OFF_RS    362496u      // [65537] int
#define OFF_H1    1048576u     // [NROWS][256] bf16 = 128 MB
#define OFF_H2    135266304u   // [NROWS][128] bf16 = 64 MB
#define OFF_G     202375168u   // [NROWS][128] bf16 = 64 MB
#define OFF_E     269484032u   // [NROWS] f32 = 1 MB
#define OFF_OBJ   270532608u   // [GSEG][128] f32 = 33 MB

// XOR-swizzle element index within a row: flip bits 3..5 by row&7.
__device__ __forceinline__ int swz(int r, int k) { return k ^ ((r & 7) << 3); }

// ---------------- prep: fold BN, transpose+convert weights to bf16 [col][k] ----------------
__global__ __launch_bounds__(256) void k_prep(
    const float* __restrict__ w2, const float* __restrict__ w3, const float* __restrict__ gw,
    const float* __restrict__ b2, const float* __restrict__ bn_g, const float* __restrict__ bn_b,
    const float* __restrict__ bn_m, const float* __restrict__ bn_v,
    bf16* __restrict__ w2t, bf16* __restrict__ w3t, bf16* __restrict__ gwt,
    float* __restrict__ bnS, float* __restrict__ bnB) {
  int idx = blockIdx.x * 256 + threadIdx.x;
  if (idx < DIN * DMID) { int k = idx / DMID, n = idx % DMID; w2t[n * DIN + k] = (bf16)w2[idx]; }
  if (idx < DMID * DGAT) { int k = idx / DGAT, n = idx % DGAT; w3t[n * DMID + k] = (bf16)w3[idx]; }
  if (idx < DGAT * DGAT) { int k = idx / DGAT, n = idx % DGAT; gwt[n * DGAT + k] = (bf16)gw[idx]; }
  if (idx < DMID) {
    float s = bn_g[idx] * rsqrtf(bn_v[idx] + 1e-5f);
    bnS[idx] = s;
    bnB[idx] = s * (b2[idx] - bn_m[idx]) + bn_b[idx];
  }
}

// ---------------- segment boundaries from sorted seg_ids ----------------
__global__ __launch_bounds__(256) void k_rowstart(const int* __restrict__ seg, int* __restrict__ rs) {
  int i = blockIdx.x * 256 + threadIdx.x;
  if (i >= NROWS) return;
  int s = seg[i];
  if (i == 0) rs[s] = 0;
  else if (seg[i - 1] != s) rs[s] = i;
  if (i == NROWS - 1) rs[GSEG] = NROWS;
}

// ---------------- GEMM1: h1 = relu(bnS * (x@w2) + bnB), bf16 out ----------------
// tile 128x256 (full width), BK=64, 4 waves (2x2), wave tile 64x128
__global__ __launch_bounds__(256) void k_gemm1(
    const float* __restrict__ x, const bf16* __restrict__ w2t,
    const float* __restrict__ bnS, const float* __restrict__ bnB,
    bf16* __restrict__ h1) {
  __shared__ bf16 As[128 * 64];   // [row][k] swizzled
  __shared__ bf16 Bs[256 * 64];   // [col][k] swizzled
  const int t = threadIdx.x;
  const int mBase = blockIdx.x * 128;
  const int w = t >> 6, l = t & 63;
  const int wm = w >> 1, wn = w & 1;

  f32x4 acc[4][8];
  const f32x4 zero = {0.f, 0.f, 0.f, 0.f};
#pragma unroll
  for (int m = 0; m < 4; m++)
#pragma unroll
    for (int n = 0; n < 8; n++) acc[m][n] = zero;

  for (int kt = 0; kt < 8; ++kt) {
    __syncthreads();
    // stage A: 128x64 fp32 -> bf16 (convert in regs)
#pragma unroll
    for (int i = 0; i < 8; i++) {
      int flat = (i * 256 + t) * 4;
      int r = flat >> 6, k = flat & 63;
      float4 v = *(const float4*)(x + (size_t)(mBase + r) * DIN + kt * 64 + k);
      bf16x4 bv;
      bv[0] = (bf16)v.x; bv[1] = (bf16)v.y; bv[2] = (bf16)v.z; bv[3] = (bf16)v.w;
      *(bf16x4*)(As + r * 64 + swz(r, k)) = bv;
    }
    // stage B: 256 cols x 64 k of w2t (already bf16)
#pragma unroll
    for (int i = 0; i < 16; i++) {
      int flat = (i * 256 + t) * 4;
      int c = flat >> 6, k = flat & 63;
      bf16x4 bv = *(const bf16x4*)(w2t + (size_t)c * DIN + kt * 64 + k);
      *(bf16x4*)(Bs + c * 64 + swz(c, k)) = bv;
    }
    __syncthreads();
#pragma unroll
    for (int ks = 0; ks < 2; ++ks) {
      const int kofs = ks * 32 + (l >> 4) * 8;
      bf16x8 a[4], b[8];
#pragma unroll
      for (int m = 0; m < 4; m++) {
        int r = wm * 64 + m * 16 + (l & 15);
        a[m] = *(const bf16x8*)(As + r * 64 + swz(r, kofs));
      }
#pragma unroll
      for (int n = 0; n < 8; n++) {
        int c = wn * 128 + n * 16 + (l & 15);
        b[n] = *(const bf16x8*)(Bs + c * 64 + swz(c, kofs));
      }
#pragma unroll
      for (int m = 0; m < 4; m++)
#pragma unroll
        for (int n = 0; n < 8; n++)
          acc[m][n] = __builtin_amdgcn_mfma_f32_16x16x32_bf16(a[m], b[n], acc[m][n], 0, 0, 0);
    }
  }
  // epilogue: BN + ReLU -> bf16
#pragma unroll
  for (int n = 0; n < 8; n++) {
    int c = wn * 128 + n * 16 + (l & 15);
    float s = bnS[c], bb = bnB[c];
#pragma unroll
    for (int m = 0; m < 4; m++) {
      int rbase = mBase + wm * 64 + m * 16 + ((l >> 4) << 2);
#pragma unroll
      for (int q = 0; q < 4; q++) {
        float v = acc[m][n][q] * s + bb;
        v = v > 0.f ? v : 0.f;
        h1[(size_t)(rbase + q) * DMID + c] = (bf16)v;
      }
    }
  }
}

// ---------------- GEMM2+3 fused: h2 = relu(h1@w3+b3); g = h2@gw+gb; e = g@ga ----------------
// tile 128x128 (full width), 4 waves (2x2), wave tile 64x64
__global__ __launch_bounds__(256) void k_gemm23(
    const bf16* __restrict__ h1, const bf16* __restrict__ w3t, const bf16* __restrict__ gwt,
    const float* __restrict__ b3, const float* __restrict__ gb, const float* __restrict__ ga,
    bf16* __restrict__ h2, bf16* __restrict__ g, float* __restrict__ e) {
  __shared__ bf16 u[16384];        // 32KB union: phase1 As(8192)+Bs(8192); phase2 Hs(16384)
  __shared__ float eP[256];        // [row][wn] partial e
  bf16* As = u;
  bf16* Bs = u + 8192;
  bf16* Hs = u;
  const int t = threadIdx.x;
  const int mBase = blockIdx.x * 128;
  const int w = t >> 6, l = t & 63;
  const int wm = w >> 1, wn = w & 1;
  const f32x4 zero = {0.f, 0.f, 0.f, 0.f};

  f32x4 acc[4][4];
#pragma unroll
  for (int m = 0; m < 4; m++)
#pragma unroll
    for (int n = 0; n < 4; n++) acc[m][n] = zero;

  // phase 1: h2 = relu(h1 @ w3 + b3), K=256
  for (int kt = 0; kt < 4; ++kt) {
    __syncthreads();
#pragma unroll
    for (int i = 0; i < 8; i++) {
      int flat = (i * 256 + t) * 4;
      int r = flat >> 6, k = flat & 63;
      *(bf16x4*)(As + r * 64 + swz(r, k)) =
          *(const bf16x4*)(h1 + (size_t)(mBase + r) * DMID + kt * 64 + k);
    }
#pragma unroll
    for (int i = 0; i < 8; i++) {
      int flat = (i * 256 + t) * 4;
      int c = flat >> 6, k = flat & 63;
      *(bf16x4*)(Bs + c * 64 + swz(c, k)) =
          *(const bf16x4*)(w3t + (size_t)c * DMID + kt * 64 + k);
    }
    __syncthreads();
#pragma unroll
    for (int ks = 0; ks < 2; ++ks) {
      const int kofs = ks * 32 + (l >> 4) * 8;
      bf16x8 a[4], b[4];
#pragma unroll
      for (int m = 0; m < 4; m++) {
        int r = wm * 64 + m * 16 + (l & 15);
        a[m] = *(const bf16x8*)(As + r * 64 + swz(r, kofs));
      }
#pragma unroll
      for (int n = 0; n < 4; n++) {
        int c = wn * 64 + n * 16 + (l & 15);
        b[n] = *(const bf16x8*)(Bs + c * 64 + swz(c, kofs));
      }
#pragma unroll
      for (int m = 0; m < 4; m++)
#pragma unroll
        for (int n = 0; n < 4; n++)
          acc[m][n] = __builtin_amdgcn_mfma_f32_16x16x32_bf16(a[m], b[n], acc[m][n], 0, 0, 0);
    }
  }
  __syncthreads();  // all waves done reading As/Bs (Hs aliases them)
  // epilogue 1: relu+bias -> bf16; write h2 global + Hs (swizzled)
#pragma unroll
  for (int n = 0; n < 4; n++) {
    int c = wn * 64 + n * 16 + (l & 15);
    float bias = b3[c];
#pragma unroll
    for (int m = 0; m < 4; m++) {
      int rloc = wm * 64 + m * 16 + ((l >> 4) << 2);
#pragma unroll
      for (int q = 0; q < 4; q++) {
        float v = acc[m][n][q] + bias;
        v = v > 0.f ? v : 0.f;
        bf16 hb = (bf16)v;
        h2[(size_t)(mBase + rloc + q) * DGAT + c] = hb;
        Hs[(rloc + q) * 128 + swz(rloc + q, c)] = hb;
      }
    }
  }
  __syncthreads();

  // phase 2: g = h2 @ gw + gb (K=128); gw B-frags streamed from L1/L2
  f32x4 gacc[4][4];
#pragma unroll
  for (int m = 0; m < 4; m++)
#pragma unroll
    for (int n = 0; n < 4; n++) gacc[m][n] = zero;
#pragma unroll
  for (int ks = 0; ks < 4; ++ks) {
    const int kofs = ks * 32 + (l >> 4) * 8;
    bf16x8 a[4], b[4];
#pragma unroll
    for (int m = 0; m < 4; m++) {
      int r = wm * 64 + m * 16 + (l & 15);
      a[m] = *(const bf16x8*)(Hs + r * 128 + swz(r, kofs));
    }
#pragma unroll
    for (int n = 0; n < 4; n++) {
      int c = wn * 64 + n * 16 + (l & 15);
      b[n] = *(const bf16x8*)(gwt + (size_t)c * DGAT + kofs);
    }
#pragma unroll
    for (int m = 0; m < 4; m++)
#pragma unroll
      for (int n = 0; n < 4; n++)
        gacc[m][n] = __builtin_amdgcn_mfma_f32_16x16x32_bf16(a[m], b[n], gacc[m][n], 0, 0, 0);
  }
  // epilogue 2: g (bf16-rounded) write + e = g_rounded . ga (consistent with pooling)
  float ep[4][4];
#pragma unroll
  for (int m = 0; m < 4; m++)
#pragma unroll
    for (int q = 0; q < 4; q++) ep[m][q] = 0.f;
#pragma unroll
  for (int n = 0; n < 4; n++) {
    int c = wn * 64 + n * 16 + (l & 15);
    float gbv = gb[c], gav = ga[c];
#pragma unroll
    for (int m = 0; m < 4; m++) {
      int rloc = wm * 64 + m * 16 + ((l >> 4) << 2);
#pragma unroll
      for (int q = 0; q < 4; q++) {
        bf16 gbq = (bf16)(gacc[m][n][q] + gbv);
        g[(size_t)(mBase + rloc + q) * DGAT + c] = gbq;
        ep[m][q] += (float)gbq * gav;
      }
    }
  }
#pragma unroll
  for (int m = 0; m < 4; m++)
#pragma unroll
    for (int q = 0; q < 4; q++) {
      float v = ep[m][q];
      v += __shfl_xor(v, 8, 16);
      v += __shfl_xor(v, 4, 16);
      v += __shfl_xor(v, 2, 16);
      v += __shfl_xor(v, 1, 16);
      if ((l & 15) == 0) {
        int rloc = wm * 64 + m * 16 + ((l >> 4) << 2) + q;
        eP[rloc * 2 + wn] = v;
      }
    }
  __syncthreads();
  if (t < 128) e[mBase + t] = eP[t * 2] + eP[t * 2 + 1];
}

// ---------------- segment softmax-pool + residual + segment max ----------------
// one wave per segment
__global__ __launch_bounds__(256) void k_seg(
    const float* __restrict__ e, const bf16* __restrict__ g, const bf16* __restrict__ h2,
    const int* __restrict__ rs, float* __restrict__ obj) {
  const int w = threadIdx.x >> 6, l = threadIdx.x & 63;
  const int s = blockIdx.x * 4 + w;
  const int r0 = rs[s], r1 = rs[s + 1];
  float m = -3.4e38f;
  for (int r = r0; r < r1; ++r) m = fmaxf(m, e[r]);
  float den = 0.f;
  f32x2 p = {0.f, 0.f};
  for (int r = r0; r < r1; ++r) {
    float wr = __expf(e[r] - m);
    den += wr;
    bf16x2 gv = *(const bf16x2*)(g + (size_t)r * DGAT + l * 2);
    p[0] += wr * (float)gv[0];
    p[1] += wr * (float)gv[1];
  }
  float inv = 1.f / den;
  p[0] *= inv; p[1] *= inv;
  f32x2 om = {0.f, 0.f};  // relu output >= 0, at least one row
  for (int r = r0; r < r1; ++r) {
    bf16x2 hv = *(const bf16x2*)(h2 + (size_t)r * DGAT + l * 2);
    om[0] = fmaxf(om[0], fmaxf((float)hv[0] + p[0], 0.f));
    om[1] = fmaxf(om[1], fmaxf((float)hv[1] + p[1], 0.f));
  }
  *(f32x2*)(obj + (size_t)s * DGAT + l * 2) = om;
}

// ---------------- projection + L2 norm: out = normalize(obj @ pw + pb) ----------------
__global__ __launch_bounds__(256) void k_proj(
    const float* __restrict__ obj, const float* __restrict__ pw, const float* __restrict__ pb,
    float* __restrict__ out) {
  __shared__ float objs[16 * 128];
  __shared__ float red[16 * 4];
  const int t = threadIdx.x;
  const int gBase = blockIdx.x * 16;
#pragma unroll
  for (int i = 0; i < 8; i++) {
    int idx = i * 256 + t;
    objs[idx] = obj[(size_t)gBase * 128 + idx];
  }
  __syncthreads();
  float acc[16];
#pragma unroll
  for (int r = 0; r < 16; r++) acc[r] = 0.f;
  for (int k4 = 0; k4 < 32; k4++) {
    float p0 = pw[(k4 * 4 + 0) * 256 + t];
    float p1 = pw[(k4 * 4 + 1) * 256 + t];
    float p2 = pw[(k4 * 4 + 2) * 256 + t];
    float p3 = pw[(k4 * 4 + 3) * 256 + t];
#pragma unroll
    for (int r = 0; r < 16; r++) {
      f32x4 o = *(const f32x4*)(objs + r * 128 + k4 * 4);
      acc[r] += o[0] * p0 + o[1] * p1 + o[2] * p2 + o[3] * p3;
    }
  }
  const float pbv = pb[t];
  const int w = t >> 6, l = t & 63;
#pragma unroll
  for (int r = 0; r < 16; r++) {
    acc[r] += pbv;
    float s2 = acc[r] * acc[r];
#pragma unroll
    for (int off = 32; off >= 1; off >>= 1) s2 += __shfl_xor(s2, off, 64);
    if (l == 0) red[r * 4 + w] = s2;
  }
  __syncthreads();
#pragma unroll
  for (int r = 0; r < 16; r++) {
    float tot = red[r * 4] + red[r * 4 + 1] + red[r * 4 + 2] + red[r * 4 + 3];
    float rinv = 1.f / (sqrtf(tot) + 1e-9f);
    out[(size_t)(gBase + r) * 256 + t] = acc[r] * rinv;
  }
}

extern "C" void kernel_launch(void* const* d_in, const int* in_sizes, int n_in,
                              void* d_out, int out_size, void* d_ws, size_t ws_size,
                              hipStream_t stream) {
  const float* x    = (const float*)d_in[0];
  const int*   seg  = (const int*)d_in[1];
  const float* w2   = (const float*)d_in[2];
  const float* b2   = (const float*)d_in[3];
  const float* bn_g = (const float*)d_in[4];
  const float* bn_b = (const float*)d_in[5];
  const float* bn_m = (const float*)d_in[6];
  const float* bn_v = (const float*)d_in[7];
  const float* w3   = (const float*)d_in[8];
  const float* b3   = (const float*)d_in[9];
  const float* gw   = (const float*)d_in[10];
  const float* gb   = (const float*)d_in[11];
  const float* ga   = (const float*)d_in[12];
  const float* pw   = (const float*)d_in[13];
  const float* pb   = (const float*)d_in[14];

  char* ws = (char*)d_ws;
  bf16*  w2t = (bf16*)(ws + OFF_W2T);
  bf16*  w3t = (bf16*)(ws + OFF_W3T);
  bf16*  gwt = (bf16*)(ws + OFF_GWT);
  float* bnS = (float*)(ws + OFF_BNS);
  float* bnB = (float*)(ws + OFF_BNB);
  int*   rs  = (int*)(ws + OFF_RS);
  bf16*  h1  = (bf16*)(ws + OFF_H1);
  bf16*  h2  = (bf16*)(ws + OFF_H2);
  bf16*  g   = (bf16*)(ws + OFF_G);
  float* e   = (float*)(ws + OFF_E);
  float* obj = (float*)(ws + OFF_OBJ);
  float* out = (float*)d_out;

  k_prep<<<512, 256, 0, stream>>>(w2, w3, gw, b2, bn_g, bn_b, bn_m, bn_v, w2t, w3t, gwt, bnS, bnB);
  k_rowstart<<<NROWS / 256, 256, 0, stream>>>(seg, rs);
  k_gemm1<<<NROWS / 128, 256, 0, stream>>>(x, w2t, bnS, bnB, h1);
  k_gemm23<<<NROWS / 128, 256, 0, stream>>>(h1, w3t, gwt, b3, gb, ga, h2, g, e);
  k_seg<<<GSEG / 4, 256, 0, stream>>>(e, g, h2, rs, obj);
  k_proj<<<GSEG / 16, 256, 0, stream>>>(obj, pw, pb, out);
}

// Round 4
// 427.845 us; speedup vs baseline: 1.3305x; 1.0739x over previous
//
#include <hip/hip_runtime.h>
#include <hip/hip_bf16.h>
#include <stdint.h>

typedef __bf16 bf16;
typedef __bf16 bf16x2 __attribute__((ext_vector_type(2)));
typedef __bf16 bf16x4 __attribute__((ext_vector_type(4)));
typedef __bf16 bf16x8 __attribute__((ext_vector_type(8)));
typedef float  f32x4  __attribute__((ext_vector_type(4)));
typedef float  f32x2  __attribute__((ext_vector_type(2)));

#define NROWS 262144
#define GSEG  65536
#define DIN   512
#define DMID  256
#define DGAT  128
#define DOUT  256

// ---- workspace layout (bytes) ----
#define OFF_W2S   0u           // [256][512] bf16, K pre-swizzled
#define OFF_W3S   262144u      // [128][256] bf16, K pre-swizzled
#define OFF_GWT   327680u      // [128][128] bf16, plain [col][k]
#define OFF_BNS   360448u      // [256] f32
#define OFF_BNB   361472u      // [256] f32
#define OFF_RS    362496u      // [65537] int
#define OFF_H1    1048576u     // [NROWS][256] bf16, K pre-swizzled (internal layout)
#define OFF_H2    135266304u   // [NROWS][128] bf16
#define OFF_G     202375168u   // [NROWS][128] bf16
#define OFF_E     269484032u   // [NROWS] f32
#define OFF_OBJ   270532608u   // [GSEG][128] f32

#define GLOAD16(gptr, lptr) __builtin_amdgcn_global_load_lds( \
    (const __attribute__((address_space(1))) void*)(gptr),    \
    (__attribute__((address_space(3))) void*)(lptr), 16, 0, 0)

// ---------------- prep: fold BN; transpose+convert weights, K-swizzled ----------------
__global__ __launch_bounds__(256) void k_prep(
    const float* __restrict__ w2, const float* __restrict__ w3, const float* __restrict__ gw,
    const float* __restrict__ b2, const float* __restrict__ bn_g, const float* __restrict__ bn_b,
    const float* __restrict__ bn_m, const float* __restrict__ bn_v,
    bf16* __restrict__ w2s, bf16* __restrict__ w3s, bf16* __restrict__ gwt,
    float* __restrict__ bnS, float* __restrict__ bnB) {
  int idx = blockIdx.x * 256 + threadIdx.x;
  if (idx < DIN * DMID) {
    int k = idx / DMID, c = idx % DMID;
    int kk = k & 63, kb = k & ~63;
    w2s[c * DIN + kb + (kk ^ ((c & 7) << 3))] = (bf16)w2[idx];
  }
  if (idx < DMID * DGAT) {
    int k = idx / DGAT, c = idx % DGAT;
    int kk = k & 63, kb = k & ~63;
    w3s[c * DMID + kb + (kk ^ ((c & 7) << 3))] = (bf16)w3[idx];
  }
  if (idx < DGAT * DGAT) {
    int k = idx / DGAT, c = idx % DGAT;
    gwt[c * DGAT + k] = (bf16)gw[idx];
  }
  if (idx < DMID) {
    float s = bn_g[idx] * rsqrtf(bn_v[idx] + 1e-5f);
    bnS[idx] = s;
    bnB[idx] = s * (b2[idx] - bn_m[idx]) + bn_b[idx];
  }
}

// ---------------- segment boundaries ----------------
__global__ __launch_bounds__(256) void k_rowstart(const int* __restrict__ seg, int* __restrict__ rs) {
  int i = blockIdx.x * 256 + threadIdx.x;
  if (i >= NROWS) return;
  int s = seg[i];
  if (i == 0) rs[s] = 0;
  else if (seg[i - 1] != s) rs[s] = i;
  if (i == NROWS - 1) rs[GSEG] = NROWS;
}

// ---------------- GEMM1: h1s = relu(bnS*(x@w2)+bnB), written K-pre-swizzled ----------------
// tile 128x256 (full width), BK=64, 4 waves (2x2), wave tile 64x128.
// A: reg-staged fp32->bf16 into swizzled LDS (prefetched). B: global_load_lds from w2s.
__global__ __launch_bounds__(256, 2) void k_gemm1(
    const float* __restrict__ x, const bf16* __restrict__ w2s,
    const float* __restrict__ bnS, const float* __restrict__ bnB,
    bf16* __restrict__ h1s) {
  __shared__ bf16 As[128 * 64];   // 16 KB
  __shared__ bf16 Bs[256 * 64];   // 32 KB (linear dest = swizzled content)
  const int t = threadIdx.x;
  const int mBase = blockIdx.x * 128;
  const int w = t >> 6, l = t & 63;
  const int l15 = l & 15, lh = l >> 4;
  const int wm = w >> 1, wn = w & 1;

  // A staging: thread t -> row ar, 32 fp32 at ak
  const int ar = t >> 1;
  const int ak = (t & 1) * 32;
  const float* xp = x + (size_t)(mBase + ar) * DIN + ak;
  const int aswz = (ar & 7) << 3;
  // B gload: 8 issues/wave, lane: col = w*64+i*8 + l/8, kk = (l&7)*8
  const int bcol0 = w * 64 + (l >> 3);
  const int bkk = (l & 7) * 8;

  f32x4 acc[4][8];
  const f32x4 zero = {0.f, 0.f, 0.f, 0.f};
#pragma unroll
  for (int m = 0; m < 4; m++)
#pragma unroll
    for (int n = 0; n < 8; n++) acc[m][n] = zero;

  float4 pf[8];
#pragma unroll
  for (int j = 0; j < 8; j++) pf[j] = *(const float4*)(xp + j * 4);

  for (int kt = 0; kt < 8; ++kt) {
    // convert prefetched A to bf16
    bf16x8 av[4];
#pragma unroll
    for (int j = 0; j < 4; j++) {
      av[j][0] = (bf16)pf[2 * j].x; av[j][1] = (bf16)pf[2 * j].y;
      av[j][2] = (bf16)pf[2 * j].z; av[j][3] = (bf16)pf[2 * j].w;
      av[j][4] = (bf16)pf[2 * j + 1].x; av[j][5] = (bf16)pf[2 * j + 1].y;
      av[j][6] = (bf16)pf[2 * j + 1].z; av[j][7] = (bf16)pf[2 * j + 1].w;
    }
    __syncthreads();   // previous compute done; LDS free
#pragma unroll
    for (int j = 0; j < 4; j++)
      *(bf16x8*)(As + ar * 64 + ((ak + 8 * j) ^ aswz)) = av[j];
#pragma unroll
    for (int i = 0; i < 8; i++) {
      GLOAD16(w2s + (size_t)(bcol0 + i * 8) * DIN + kt * 64 + bkk,
              Bs + (w * 8 + i) * 512);
    }
    __syncthreads();   // drain staging
    // prefetch next x tile (overlaps MFMA)
    if (kt < 7) {
#pragma unroll
      for (int j = 0; j < 8; j++) pf[j] = *(const float4*)(xp + (kt + 1) * 64 + j * 4);
    }
#pragma unroll
    for (int ks = 0; ks < 2; ++ks) {
      const int kofs = ks * 32 + lh * 8;
      bf16x8 a[4], b[8];
#pragma unroll
      for (int m = 0; m < 4; m++) {
        int r = wm * 64 + m * 16 + l15;
        a[m] = *(const bf16x8*)(As + r * 64 + (kofs ^ ((r & 7) << 3)));
      }
#pragma unroll
      for (int n = 0; n < 8; n++) {
        int c = wn * 128 + n * 16 + l15;
        b[n] = *(const bf16x8*)(Bs + c * 64 + (kofs ^ ((c & 7) << 3)));
      }
#pragma unroll
      for (int m = 0; m < 4; m++)
#pragma unroll
        for (int n = 0; n < 8; n++)
          acc[m][n] = __builtin_amdgcn_mfma_f32_16x16x32_bf16(b[n], a[m], acc[m][n], 0, 0, 0);
    }
  }
  // epilogue: lane holds row r, 4 consecutive cols; write h1s K-pre-swizzled
  const int rsw = (l15 & 7) << 3;
#pragma unroll
  for (int n = 0; n < 8; n++) {
    int c0 = wn * 128 + n * 16 + lh * 4;
    f32x4 s4 = *(const f32x4*)(bnS + c0);
    f32x4 b4 = *(const f32x4*)(bnB + c0);
    int kt0 = c0 & ~63, kk0 = c0 & 63;
    int cs = kt0 + (kk0 ^ rsw);
#pragma unroll
    for (int m = 0; m < 4; m++) {
      int r = mBase + wm * 64 + m * 16 + l15;
      bf16x4 o;
#pragma unroll
      for (int q = 0; q < 4; q++) {
        float v = acc[m][n][q] * s4[q] + b4[q];
        o[q] = (bf16)(v > 0.f ? v : 0.f);
      }
      *(bf16x4*)(h1s + (size_t)r * DMID + cs) = o;
    }
  }
}

// ---------------- GEMM2+3 fused ----------------
// tile 128x128, 4 waves (2x2), wave tile 64x64. A & B both via global_load_lds
// (pre-swizzled sources). Phase2 B-frags from L2-resident gwt. Swapped MFMA.
__global__ __launch_bounds__(256) void k_gemm23(
    const bf16* __restrict__ h1s, const bf16* __restrict__ w3s, const bf16* __restrict__ gwt,
    const float* __restrict__ b3, const float* __restrict__ gb, const float* __restrict__ ga,
    bf16* __restrict__ h2, bf16* __restrict__ g, float* __restrict__ e) {
  __shared__ bf16 u[16384];        // 32KB: phase1 As(16KB)+Bs(16KB); phase2 Hs(32KB)
  __shared__ float eP[256];
  bf16* As = u;
  bf16* Bs = u + 8192;
  bf16* Hs = u;
  const int t = threadIdx.x;
  const int mBase = blockIdx.x * 128;
  const int w = t >> 6, l = t & 63;
  const int wm = w >> 1, wn = w & 1;
  const int l15 = l & 15, lh = l >> 4;
  const f32x4 zero = {0.f, 0.f, 0.f, 0.f};

  const int grow0 = w * 32 + (l >> 3);   // gload: row/col = w*32+i*8 + l/8
  const int gkk = (l & 7) * 8;

  f32x4 acc[4][4];
#pragma unroll
  for (int m = 0; m < 4; m++)
#pragma unroll
    for (int n = 0; n < 4; n++) acc[m][n] = zero;

  // phase 1: h2 = relu(h1 @ w3 + b3), K=256
  for (int kt = 0; kt < 4; ++kt) {
    __syncthreads();
#pragma unroll
    for (int i = 0; i < 4; i++) {
      GLOAD16(h1s + (size_t)(mBase + grow0 + i * 8) * DMID + kt * 64 + gkk,
              As + (w * 4 + i) * 512);
      GLOAD16(w3s + (size_t)(grow0 + i * 8) * DMID + kt * 64 + gkk,
              Bs + (w * 4 + i) * 512);
    }
    __syncthreads();
#pragma unroll
    for (int ks = 0; ks < 2; ++ks) {
      const int kofs = ks * 32 + lh * 8;
      bf16x8 a[4], b[4];
#pragma unroll
      for (int m = 0; m < 4; m++) {
        int r = wm * 64 + m * 16 + l15;
        a[m] = *(const bf16x8*)(As + r * 64 + (kofs ^ ((r & 7) << 3)));
      }
#pragma unroll
      for (int n = 0; n < 4; n++) {
        int c = wn * 64 + n * 16 + l15;
        b[n] = *(const bf16x8*)(Bs + c * 64 + (kofs ^ ((c & 7) << 3)));
      }
#pragma unroll
      for (int m = 0; m < 4; m++)
#pragma unroll
        for (int n = 0; n < 4; n++)
          acc[m][n] = __builtin_amdgcn_mfma_f32_16x16x32_bf16(b[n], a[m], acc[m][n], 0, 0, 0);
    }
  }
  __syncthreads();  // all MFMA reads done; Hs aliases As/Bs

  // epilogue 1: relu+bias -> bf16; packed stores to h2 and Hs (swizzled)
#pragma unroll
  for (int n = 0; n < 4; n++) {
    int c0 = wn * 64 + n * 16 + lh * 4;
    f32x4 b4 = *(const f32x4*)(b3 + c0);
#pragma unroll
    for (int m = 0; m < 4; m++) {
      int rl = wm * 64 + m * 16 + l15;
      bf16x4 hb;
#pragma unroll
      for (int q = 0; q < 4; q++) {
        float v = acc[m][n][q] + b4[q];
        hb[q] = (bf16)(v > 0.f ? v : 0.f);
      }
      *(bf16x4*)(h2 + (size_t)(mBase + rl) * DGAT + c0) = hb;
      *(bf16x4*)(Hs + rl * 128 + (c0 ^ ((rl & 7) << 3))) = hb;
    }
  }
  __syncthreads();

  // phase 2: g = h2 @ gw + gb (K=128); gw frags from L2
  f32x4 gacc[4][4];
#pragma unroll
  for (int m = 0; m < 4; m++)
#pragma unroll
    for (int n = 0; n < 4; n++) gacc[m][n] = zero;
#pragma unroll
  for (int ks = 0; ks < 4; ++ks) {
    const int kofs = ks * 32 + lh * 8;
    bf16x8 a[4], b[4];
#pragma unroll
    for (int n = 0; n < 4; n++) {
      int c = wn * 64 + n * 16 + l15;
      b[n] = *(const bf16x8*)(gwt + (size_t)c * DGAT + kofs);
    }
#pragma unroll
    for (int m = 0; m < 4; m++) {
      int r = wm * 64 + m * 16 + l15;
      a[m] = *(const bf16x8*)(Hs + r * 128 + (kofs ^ ((r & 7) << 3)));
    }
#pragma unroll
    for (int m = 0; m < 4; m++)
#pragma unroll
      for (int n = 0; n < 4; n++)
        gacc[m][n] = __builtin_amdgcn_mfma_f32_16x16x32_bf16(b[n], a[m], gacc[m][n], 0, 0, 0);
  }
  // epilogue 2: packed bf16 g stores + e from rounded g
  float ep[4] = {0.f, 0.f, 0.f, 0.f};
#pragma unroll
  for (int n = 0; n < 4; n++) {
    int c0 = wn * 64 + n * 16 + lh * 4;
    f32x4 gb4 = *(const f32x4*)(gb + c0);
    f32x4 ga4 = *(const f32x4*)(ga + c0);
#pragma unroll
    for (int m = 0; m < 4; m++) {
      int rl = wm * 64 + m * 16 + l15;
      bf16x4 gv;
#pragma unroll
      for (int q = 0; q < 4; q++) gv[q] = (bf16)(gacc[m][n][q] + gb4[q]);
      *(bf16x4*)(g + (size_t)(mBase + rl) * DGAT + c0) = gv;
#pragma unroll
      for (int q = 0; q < 4; q++) ep[m] += (float)gv[q] * ga4[q];
    }
  }
#pragma unroll
  for (int m = 0; m < 4; m++) {
    float v = ep[m];
    v += __shfl_xor(v, 16, 64);
    v += __shfl_xor(v, 32, 64);
    if (l < 16) eP[(wm * 64 + m * 16 + l) * 2 + wn] = v;
  }
  __syncthreads();
  if (t < 128) e[mBase + t] = eP[t * 2] + eP[t * 2 + 1];
}

// ---------------- segment softmax-pool + residual + segment max ----------------
__global__ __launch_bounds__(256) void k_seg(
    const float* __restrict__ e, const bf16* __restrict__ g, const bf16* __restrict__ h2,
    const int* __restrict__ rs, float* __restrict__ obj) {
  const int w = threadIdx.x >> 6, l = threadIdx.x & 63;
  const int s = blockIdx.x * 4 + w;
  const int r0 = rs[s], r1 = rs[s + 1];
  float m = -3.4e38f;
  for (int r = r0; r < r1; ++r) m = fmaxf(m, e[r]);
  float den = 0.f;
  f32x2 p = {0.f, 0.f};
  for (int r = r0; r < r1; ++r) {
    float wr = __expf(e[r] - m);
    den += wr;
    bf16x2 gv = *(const bf16x2*)(g + (size_t)r * DGAT + l * 2);
    p[0] += wr * (float)gv[0];
    p[1] += wr * (float)gv[1];
  }
  float inv = 1.f / den;
  p[0] *= inv; p[1] *= inv;
  f32x2 om = {0.f, 0.f};
  for (int r = r0; r < r1; ++r) {
    bf16x2 hv = *(const bf16x2*)(h2 + (size_t)r * DGAT + l * 2);
    om[0] = fmaxf(om[0], fmaxf((float)hv[0] + p[0], 0.f));
    om[1] = fmaxf(om[1], fmaxf((float)hv[1] + p[1], 0.f));
  }
  *(f32x2*)(obj + (size_t)s * DGAT + l * 2) = om;
}

// ---------------- projection + L2 norm ----------------
__global__ __launch_bounds__(256) void k_proj(
    const float* __restrict__ obj, const float* __restrict__ pw, const float* __restrict__ pb,
    float* __restrict__ out) {
  __shared__ float objs[16 * 128];
  __shared__ float red[16 * 4];
  const int t = threadIdx.x;
  const int gBase = blockIdx.x * 16;
#pragma unroll
  for (int i = 0; i < 8; i++) {
    int idx = i * 256 + t;
    objs[idx] = obj[(size_t)gBase * 128 + idx];
  }
  __syncthreads();
  float acc[16];
#pragma unroll
  for (int r = 0; r < 16; r++) acc[r] = 0.f;
  for (int k4 = 0; k4 < 32; k4++) {
    float p0 = pw[(k4 * 4 + 0) * 256 + t];
    float p1 = pw[(k4 * 4 + 1) * 256 + t];
    float p2 = pw[(k4 * 4 + 2) * 256 + t];
    float p3 = pw[(k4 * 4 + 3) * 256 + t];
#pragma unroll
    for (int r = 0; r < 16; r++) {
      f32x4 o = *(const f32x4*)(objs + r * 128 + k4 * 4);
      acc[r] += o[0] * p0 + o[1] * p1 + o[2] * p2 + o[3] * p3;
    }
  }
  const float pbv = pb[t];
  const int w = t >> 6, l = t & 63;
#pragma unroll
  for (int r = 0; r < 16; r++) {
    acc[r] += pbv;
    float s2 = acc[r] * acc[r];
#pragma unroll
    for (int off = 32; off >= 1; off >>= 1) s2 += __shfl_xor(s2, off, 64);
    if (l == 0) red[r * 4 + w] = s2;
  }
  __syncthreads();
#pragma unroll
  for (int r = 0; r < 16; r++) {
    float tot = red[r * 4] + red[r * 4 + 1] + red[r * 4 + 2] + red[r * 4 + 3];
    float rinv = 1.f / (sqrtf(tot) + 1e-9f);
    out[(size_t)(gBase + r) * 256 + t] = acc[r] * rinv;
  }
}

extern "C" void kernel_launch(void* const* d_in, const int* in_sizes, int n_in,
                              void* d_out, int out_size, void* d_ws, size_t ws_size,
                              hipStream_t stream) {
  const float* x    = (const float*)d_in[0];
  const int*   seg  = (const int*)d_in[1];
  const float* w2   = (const float*)d_in[2];
  const float* b2   = (const float*)d_in[3];
  const float* bn_g = (const float*)d_in[4];
  const float* bn_b = (const float*)d_in[5];
  const float* bn_m = (const float*)d_in[6];
  const float* bn_v = (const float*)d_in[7];
  const float* w3   = (const float*)d_in[8];
  const float* b3   = (const float*)d_in[9];
  const float* gw   = (const float*)d_in[10];
  const float* gb   = (const float*)d_in[11];
  const float* ga   = (const float*)d_in[12];
  const float* pw   = (const float*)d_in[13];
  const float* pb   = (const float*)d_in[14];

  char* ws = (char*)d_ws;
  bf16*  w2s = (bf16*)(ws + OFF_W2S);
  bf16*  w3s = (bf16*)(ws + OFF_W3S);
  bf16*  gwt = (bf16*)(ws + OFF_GWT);
  float* bnS = (float*)(ws + OFF_BNS);
  float* bnB = (float*)(ws + OFF_BNB);
  int*   rs  = (int*)(ws + OFF_RS);
  bf16*  h1s = (bf16*)(ws + OFF_H1);
  bf16*  h2  = (bf16*)(ws + OFF_H2);
  bf16*  g   = (bf16*)(ws + OFF_G);
  float* e   = (float*)(ws + OFF_E);
  float* obj = (float*)(ws + OFF_OBJ);
  float* out = (float*)d_out;

  k_prep<<<512, 256, 0, stream>>>(w2, w3, gw, b2, bn_g, bn_b, bn_m, bn_v, w2s, w3s, gwt, bnS, bnB);
  k_rowstart<<<NROWS / 256, 256, 0, stream>>>(seg, rs);
  k_gemm1<<<NROWS / 128, 256, 0, stream>>>(x, w2s, bnS, bnB, h1s);
  k_gemm23<<<NROWS / 128, 256, 0, stream>>>(h1s, w3s, gwt, b3, gb, ga, h2, g, e);
  k_seg<<<GSEG / 4, 256, 0, stream>>>(e, g, h2, rs, obj);
  k_proj<<<GSEG / 16, 256, 0, stream>>>(obj, pw, pb, out);
}